// Round 3
// baseline (173.286 us; speedup 1.0000x reference)
//
#include <hip/hip_runtime.h>

// mixture/target/noise: (N, 2, C, T, F) float32
#define Nn 4
#define Cc 8
#define Tt 256
#define Ff 513
#define TFs (Tt * Ff)      // 131328
#define NPAIR 36           // upper triangle of 8x8 Hermitian

// ---------------------------------------------------------------------------
// Stage 1: partial covariances, NO atomics, NO spills.
// Pair-group G handles rows {G, 7-G} of the Hermitian matrix (9 pairs).
// Partial layout: [inp][n][chunk][p][ri][f]  (f contiguous -> coalesced)
// ---------------------------------------------------------------------------
template <int G>
__device__ __forceinline__ void cov_body(const float* __restrict__ base,
                                         float* __restrict__ dst,
                                         int t0, int tchunk)
{
    constexpr int R2 = 7 - G;
    float ar[9], ai[9];
#pragma unroll
    for (int s = 0; s < 9; ++s) { ar[s] = 0.f; ai[s] = 0.f; }

    const float* bt = base + (size_t)t0 * Ff;
    for (int tt = 0; tt < tchunk; ++tt) {
        float re[8], im[8];
#pragma unroll
        for (int c = G; c < 8; ++c) {
            re[c] = bt[(size_t)c * TFs];
            im[c] = bt[(size_t)(Cc + c) * TFs];
        }
        int s = 0;
#pragma unroll
        for (int d = G; d < 8; ++d, ++s) {     // row G
            ar[s] += re[G] * re[d] + im[G] * im[d];
            ai[s] += im[G] * re[d] - re[G] * im[d];
        }
#pragma unroll
        for (int d = R2; d < 8; ++d, ++s) {    // row 7-G
            ar[s] += re[R2] * re[d] + im[R2] * im[d];
            ai[s] += im[R2] * re[d] - re[R2] * im[d];
        }
        bt += Ff;
    }

    int s = 0;
#pragma unroll
    for (int d = G; d < 8; ++d, ++s) {
        const int p = G * 8 - G * (G - 1) / 2 + (d - G);
        dst[(size_t)(p * 2 + 0) * Ff] = ar[s];
        dst[(size_t)(p * 2 + 1) * Ff] = ai[s];
    }
#pragma unroll
    for (int d = R2; d < 8; ++d, ++s) {
        const int p = R2 * 8 - R2 * (R2 - 1) / 2 + (d - R2);
        dst[(size_t)(p * 2 + 0) * Ff] = ar[s];
        dst[(size_t)(p * 2 + 1) * Ff] = ai[s];
    }
}

__global__ __launch_bounds__(64) void cov_partial(
    const float* __restrict__ target, const float* __restrict__ noise,
    float* __restrict__ partial, int nchunk, int tchunk)
{
    int f = blockIdx.x * 64 + threadIdx.x;
    if (f >= Ff) return;
    int n = blockIdx.y;
    int z = blockIdx.z;
    int g = z & 3;
    int inp = (z >> 2) & 1;
    int chunk = z >> 3;

    const float* src = inp ? noise : target;
    const float* base = src + (size_t)n * 2 * Cc * TFs + f;
    float* dst = partial +
        ((((size_t)inp * Nn + n) * nchunk + chunk) * (NPAIR * 2)) * Ff + f;
    int t0 = chunk * tchunk;

    switch (g) {
        case 0: cov_body<0>(base, dst, t0, tchunk); break;
        case 1: cov_body<1>(base, dst, t0, tchunk); break;
        case 2: cov_body<2>(base, dst, t0, tchunk); break;
        default: cov_body<3>(base, dst, t0, tchunk); break;
    }
}

// ---------------------------------------------------------------------------
// Stage 2: register-resident Gauss-Jordan solve of phiN * G = phiT.
// One wave (64 lanes) = 4 problems; 16 lanes per problem = 16 columns of the
// augmented [phiN | phiT] matrix; each lane holds its column (8 complex) in
// VGPRs. Pivot/factor broadcasts via __shfl(width=16); no barriers in the
// elimination loop. Right half becomes G = inv(phiN) @ phiT directly.
// grid: (ceil(F/4), N), block 64.
// ---------------------------------------------------------------------------
__global__ __launch_bounds__(64) void mvdr_weights(
    const float* __restrict__ partial, const int* __restrict__ ref_ptr,
    float2* __restrict__ wconj, int nchunk)
{
    const int lane = threadIdx.x;
    const int n = blockIdx.y;
    const int fbase = blockIdx.x * 4;

    __shared__ float cov[4][144];   // [prob][ target 72 | noise 72 ]

    // ---- stage: reduce chunks into LDS. lane -> (prob = lane&3, j = lane>>2)
    {
        int prob = lane & 3;
        int j = lane >> 2;          // 0..15, each covers 9 of the 144 sums
        int f = fbase + prob;
#pragma unroll
        for (int s = 0; s < 9; ++s) {
            int v = j * 9 + s;      // 0..143
            int inp = v >= 72;
            int p = inp ? v - 72 : v;
            float acc = 0.f;
            if (f < Ff) {
                for (int ch = 0; ch < nchunk; ++ch) {
                    size_t idx = ((((size_t)inp * Nn + n) * nchunk + ch) * 72 + p)
                                 * Ff + f;
                    acc += partial[idx];
                }
            }
            cov[prob][v] = acc;
        }
    }
    __syncthreads();   // single wave: near-free

    // ---- build column registers. lane -> (prob = lane>>4, col = lane&15)
    const int prob = lane >> 4;
    const int col = lane & 15;
    const int f = fbase + prob;

    const float invT = 1.0f / (float)Tt;
    const float dl = 0.001f / 1.41421356237309515f;  // 0.001/sqrt(2)

    float Ar[8], Ai[8];
    {
        const bool left = (col < 8);            // left = phiN, right = phiT
        const int c = left ? col : col - 8;
        const float* cv = &cov[prob][left ? 72 : 0];
#pragma unroll
        for (int r = 0; r < 8; ++r) {
            int lo = r <= c ? r : c, hi = r <= c ? c : r;
            int p = lo * 8 - lo * (lo - 1) / 2 + (hi - lo);
            float vr = cv[2 * p] * invT;
            float vi = cv[2 * p + 1] * invT;
            if (r > c) vi = -vi;                // Hermitian reconstruction
            if (left && r == c) { vr += dl; vi += dl; }  // complex diag load
            Ar[r] = vr; Ai[r] = vi;
        }
    }

    // ---- Gauss-Jordan with partial pivoting, all cross-lane via shuffles
#pragma unroll
    for (int k = 0; k < 8; ++k) {
        // pivot search on column k (every lane computes; lane k's result used)
        int best = k;
        float bm = Ar[k] * Ar[k] + Ai[k] * Ai[k];
#pragma unroll
        for (int j = 0; j < 8; ++j) {
            if (j > k) {
                float m = Ar[j] * Ar[j] + Ai[j] * Ai[j];
                if (m > bm) { bm = m; best = j; }
            }
        }
        int bk = __shfl(best, k, 16);

        // swap rows k <-> bk (uniform within the 16-lane group)
        float tr = Ar[k], ti = Ai[k];
#pragma unroll
        for (int j = 0; j < 8; ++j) {
            if (j == bk && j != k) {
                Ar[k] = Ar[j]; Ai[k] = Ai[j];
                Ar[j] = tr;    Ai[j] = ti;
            }
        }

        // scale row k by 1/pivot (pivot lives in lane k)
        float pr = __shfl(Ar[k], k, 16);
        float pi = __shfl(Ai[k], k, 16);
        float d = pr * pr + pi * pi;
        float ir = pr / d, ii = -pi / d;
        float nr = Ar[k] * ir - Ai[k] * ii;
        float ni = Ar[k] * ii + Ai[k] * ir;
        Ar[k] = nr; Ai[k] = ni;

        // eliminate all other rows; factors = column k (lane k's registers)
#pragma unroll
        for (int r = 0; r < 8; ++r) {
            float fr = __shfl(Ar[r], k, 16);
            float fi = __shfl(Ai[r], k, 16);
            if (r != k) {
                Ar[r] -= fr * Ar[k] - fi * Ai[k];
                Ai[r] -= fr * Ai[k] + fi * Ar[k];
            }
        }
    }

    // ---- trace(G): lane 8+j contributes G[j][j]; butterfly over the group
    float tlr = 0.f, tli = 0.f;
    if (col >= 8) { tlr = Ar[col - 8]; tli = Ai[col - 8]; }
#pragma unroll
    for (int off = 1; off < 16; off <<= 1) {
        tlr += __shfl_xor(tlr, off, 16);
        tli += __shfl_xor(tli, off, 16);
    }

    // ---- W = G[:,ref] / l ; store conj(W). Column ref of G lives in lane 8+ref.
    int ref = *ref_ptr;
    if (col == 8 + ref && f < Ff) {
        float den = tlr * tlr + tli * tli;
        float2* wp = wconj + ((size_t)n * Ff + f) * 8;
#pragma unroll
        for (int r = 0; r < 8; ++r) {
            float wx = (Ar[r] * tlr + Ai[r] * tli) / den;
            float wy = (Ai[r] * tlr - Ar[r] * tli) / den;
            wp[r] = make_float2(wx, -wy);   // conj(W)
        }
    }
}

// ---------------------------------------------------------------------------
// Stage 3: X_bf(n,t,f) = sum_c conj(W)(n,f,c) * y(n,c,t,f)
// ---------------------------------------------------------------------------
__global__ __launch_bounds__(256) void beamform(
    const float* __restrict__ y, const float2* __restrict__ wconj,
    float* __restrict__ out)
{
    int idx = blockIdx.x * 256 + threadIdx.x;   // < N*T*F = 525312
    int n = idx / TFs;
    int rem = idx - n * TFs;
    int t = rem / Ff;
    int f = rem - t * Ff;

    size_t base_re = (size_t)n * 2 * Cc * TFs + (size_t)t * Ff + f;
    size_t base_im = base_re + (size_t)Cc * TFs;
    const float2* w = wconj + ((size_t)n * Ff + f) * 8;

    float xr = 0.f, xi = 0.f;
#pragma unroll
    for (int c = 0; c < Cc; ++c) {
        float yre = y[base_re + (size_t)c * TFs];
        float yim = y[base_im + (size_t)c * TFs];
        float2 wc = w[c];
        xr += wc.x * yre - wc.y * yim;
        xi += wc.x * yim + wc.y * yre;
    }
    size_t ob = (size_t)n * 2 * TFs + (size_t)t * Ff + f;
    out[ob] = xr;
    out[ob + TFs] = xi;
}

extern "C" void kernel_launch(void* const* d_in, const int* in_sizes, int n_in,
                              void* d_out, int out_size, void* d_ws, size_t ws_size,
                              hipStream_t stream) {
    const float* mixture = (const float*)d_in[0];
    const float* target  = (const float*)d_in[1];
    const float* noise   = (const float*)d_in[2];
    const int*   refp    = (const int*)d_in[3];
    float* out = (float*)d_out;

    const size_t wconj_bytes = (size_t)Nn * Ff * 8 * sizeof(float2);
    int nchunk = 8;
    while (nchunk > 1 &&
           (size_t)2 * Nn * nchunk * 72 * Ff * sizeof(float) + wconj_bytes > ws_size)
        nchunk >>= 1;
    int tchunk = Tt / nchunk;

    float*  partial = (float*)d_ws;
    float2* wconj = (float2*)((char*)d_ws +
                              (size_t)2 * Nn * nchunk * 72 * Ff * sizeof(float));

    cov_partial<<<dim3(9, Nn, nchunk * 8), 64, 0, stream>>>(
        target, noise, partial, nchunk, tchunk);
    mvdr_weights<<<dim3((Ff + 3) / 4, Nn), 64, 0, stream>>>(
        partial, refp, wconj, nchunk);
    beamform<<<dim3((Nn * TFs) / 256), 256, 0, stream>>>(mixture, wconj, out);
}